// Round 10
// baseline (1102.046 us; speedup 1.0000x reference)
//
#include <hip/hip_runtime.h>
#include <hip/hip_bf16.h>
#include <stdint.h>

// Problem constants (fixed by the reference)
#define NB 16
#define NN 4096
#define NCF 64
#define NS 1024
#define NK 32
#define NPTS (NB*NS*NK)   // 524288
#define CIN 67
#define EPSV 1e-5f

// rn intrinsics: block FMA contraction so FPS/kNN distances bit-match numpy
static __device__ __forceinline__ float fmul(float a, float b){ return __fmul_rn(a,b); }
static __device__ __forceinline__ float fadd(float a, float b){ return __fadd_rn(a,b); }
static __device__ __forceinline__ float fsub(float a, float b){ return __fsub_rn(a,b); }

typedef float f2 __attribute__((ext_vector_type(2)));
#define PK_ADD(d,a,b) asm("v_pk_add_f32 %0, %1, %2" : "=v"(d) : "v"(a), "v"(b))
#define PK_MUL(d,a,b) asm("v_pk_mul_f32 %0, %1, %2" : "=v"(d) : "v"(a), "v"(b))
static __device__ __forceinline__ f2 pk_add(f2 a, f2 b){ f2 d; PK_ADD(d,a,b); return d; }

// MFMA fragment types (gfx950 16x16x32 bf16: 8 bf16 in / 4 f32 acc per lane)
typedef short bf16x8 __attribute__((ext_vector_type(8)));
typedef float f32x4 __attribute__((ext_vector_type(4)));

static __device__ __forceinline__ unsigned short f2b(float f){
  unsigned u = __float_as_uint(f);
  return (unsigned short)((u + 0x7FFFu + ((u>>16)&1u)) >> 16);  // RNE bf16
}
static __device__ __forceinline__ unsigned pack2(float a, float b){
  return (unsigned)f2b(a) | ((unsigned)f2b(b)<<16);
}
static __device__ __forceinline__ float readlane_f32(float v, int l){
  return __uint_as_float((unsigned)__builtin_amdgcn_readlane((int)__float_as_uint(v), l));
}

// ---- DPP cross-lane reductions (pure VALU) ---------------------------------
template<int CTRL>
static __device__ __forceinline__ float dppmax_f32(float x){   // 0-fill (x>=0 only)
  float o = __uint_as_float((unsigned)__builtin_amdgcn_update_dpp(
      0, (int)__float_as_uint(x), CTRL, 0xf, 0xf, true));
  return fmaxf(x, o);
}
static __device__ __forceinline__ float wave_max63_f32(float x){
  x = dppmax_f32<0x111>(x); x = dppmax_f32<0x112>(x);
  x = dppmax_f32<0x114>(x); x = dppmax_f32<0x118>(x);
  x = dppmax_f32<0x142>(x); x = dppmax_f32<0x143>(x);
  return x;
}
// row-16 max keeping own value on invalid lanes (safe for negatives)
template<int CTRL>
static __device__ __forceinline__ float dppmax_keep(float x){
  float o = __uint_as_float((unsigned)__builtin_amdgcn_update_dpp(
      (int)__float_as_uint(x), (int)__float_as_uint(x), CTRL, 0xf, 0xf, false));
  return fmaxf(x, o);
}
static __device__ __forceinline__ float row16_max_f32(float x){
  x = dppmax_keep<0x111>(x); x = dppmax_keep<0x112>(x);
  x = dppmax_keep<0x114>(x); x = dppmax_keep<0x118>(x);
  return x;
}
template<int CTRL>
static __device__ __forceinline__ f2 dppadd_f2(f2 x){
  f2 o;
  o.x = __uint_as_float((unsigned)__builtin_amdgcn_update_dpp(
      0, (int)__float_as_uint(x.x), CTRL, 0xf, 0xf, true));
  o.y = __uint_as_float((unsigned)__builtin_amdgcn_update_dpp(
      0, (int)__float_as_uint(x.y), CTRL, 0xf, 0xf, true));
  return pk_add(x, o);
}
// row-16 sum -> valid in lane (row*16+15)
static __device__ __forceinline__ f2 row16_sum_f2(f2 x){
  x = dppadd_f2<0x111>(x); x = dppadd_f2<0x112>(x);
  x = dppadd_f2<0x114>(x); x = dppadd_f2<0x118>(x);
  return x;
}
static __device__ __forceinline__ unsigned long long readlane_u64(unsigned long long v, int l){
  unsigned lo = (unsigned)__builtin_amdgcn_readlane((int)(unsigned)v, l);
  unsigned hi = (unsigned)__builtin_amdgcn_readlane((int)(unsigned)(v>>32), l);
  return ((unsigned long long)hi<<32) | lo;
}
static __device__ __forceinline__ unsigned long long wave_shr1_u64(unsigned long long x){
  unsigned lo = (unsigned)__builtin_amdgcn_update_dpp(
      0, (int)(unsigned)x, 0x138, 0xf, 0xf, true);
  unsigned hi = (unsigned)__builtin_amdgcn_update_dpp(
      0, (int)(unsigned)(x>>32), 0x138, 0xf, 0xf, true);
  return ((unsigned long long)hi<<32) | lo;
}
static __device__ __forceinline__ unsigned long long umax64(unsigned long long a,
                                                            unsigned long long b){
  return a > b ? a : b;
}

// ---------------------------------------------------------------------------
// prep: transpose points (B,CF,N)->(B,N,CF) as BF16, pack xyz4={x,y,z,sq};
// block 0 additionally converts/pads the conv weights to bf16 (folded wprep).
// ---------------------------------------------------------------------------
__global__ __launch_bounds__(256) void prep_kernel(const float* __restrict__ pts,
    const float* __restrict__ xyz, unsigned short* __restrict__ ptsT,
    float4* __restrict__ xyz4,
    const float* __restrict__ w0, const float* __restrict__ w1,
    const float* __restrict__ w2, unsigned short* __restrict__ w0p,
    unsigned short* __restrict__ w1p, unsigned short* __restrict__ w2p){
  int blk = blockIdx.x;            // 256 blocks = 16 b * 16 chunks
  int b = blk >> 4;
  int n = ((blk & 15) << 8) + threadIdx.x;
  const float* src = pts + (size_t)b*NCF*NN + n;
  float v[NCF];
  #pragma unroll
  for (int c=0;c<NCF;c++) v[c] = src[(size_t)c*NN];
  uint4* dst = (uint4*)(ptsT + ((size_t)b*NN + n)*NCF);
  #pragma unroll
  for (int j=0;j<8;j++)
    dst[j] = make_uint4(pack2(v[8*j],v[8*j+1]), pack2(v[8*j+2],v[8*j+3]),
                        pack2(v[8*j+4],v[8*j+5]), pack2(v[8*j+6],v[8*j+7]));
  const float* xp = xyz + ((size_t)b*NN + n)*3;
  float x=xp[0], y=xp[1], z=xp[2];
  float sq = fadd(fadd(fmul(x,x),fmul(y,y)),fmul(z,z));
  xyz4[(size_t)b*NN+n] = make_float4(x,y,z,sq);
  if (blk == 0){
    const int tid = threadIdx.x;
    for (int i = tid; i < 64*128; i += 256){
      int o = i >> 7, c = i & 127;
      float vv = 0.f;
      if (c < 64) vv = w0[o*CIN + 3 + c];        // features -> k0..63
      else if (c < 67) vv = w0[o*CIN + (c-64)];  // gxyz -> k64..66
      w0p[i] = f2b(vv);
    }
    for (int i = tid; i < 64*64; i += 256)  w1p[i] = f2b(w1[i]);
    for (int i = tid; i < 128*64; i += 256) w2p[i] = f2b(w2[i]);
  }
}

// ---------------------------------------------------------------------------
// FPS — R4-measured-best structure: one block per batch, 256 threads (4
// waves), CONTIGUOUS ownership [16t,16t+16) -> lane order == n order. Per
// step: packed rn distance update -> (bv,bj) strict > -> DPP f32 max ->
// readlane(63) -> ballot tie -> lowest lane wl WRITES THE SLOT ITSELF (its
// own bv/nbest are exactly the winners — no readlane(nbest,wl)) -> 1 barrier
// -> b128 read of 4 keys + 3 umax -> s4[far]. np.argmax exact.
// ---------------------------------------------------------------------------
#define FT 256
__global__ __launch_bounds__(FT) void fps_kernel(const float4* __restrict__ xyz4,
    int* __restrict__ fidx, float* __restrict__ newxyz){
  int b = blockIdx.x;
  __shared__ float4 s4[NN];                       // 64 KB {x,y,z,sq}
  __shared__ unsigned long long candK[2][4];      // parity-double-buffered keys
  const int tid = threadIdx.x;
  const int lane = tid & 63;
  const int wv = tid >> 6;
  for (int i = tid; i < NN; i += FT)
    s4[i] = xyz4[(size_t)b*NN + i];
  __syncthreads();
  // pair m: .x -> n = 16*tid + 2m, .y -> n = 16*tid + 2m + 1 (ascending)
  f2 px[8], py[8], pz[8], d2[8];
  #pragma unroll
  for (int m=0;m<8;m++){
    float4 a = s4[tid*16 + 2*m];
    float4 c = s4[tid*16 + 2*m + 1];
    px[m] = (f2){a.x, c.x};
    py[m] = (f2){a.y, c.y};
    pz[m] = (f2){a.z, c.z};
    d2[m] = (f2){1e10f, 1e10f};
  }
  int far = 0;
  float4 cc = s4[0];
  for (int s=0;s<NS;s++){
    if (tid==0){
      fidx[b*NS+s] = far;
      float* o = newxyz + ((size_t)b*NS+s)*3;
      o[0]=cc.x; o[1]=cc.y; o[2]=cc.z;
    }
    f2 ncx = (f2){-cc.x,-cc.x}, ncy = (f2){-cc.y,-cc.y}, ncz = (f2){-cc.z,-cc.z};
    float bv = -1.0f; int bj = 0;
    #pragma unroll
    for (int m=0;m<8;m++){
      f2 dx,dy,dz,xx,yy,zz,ss,dd;
      PK_ADD(dx, px[m], ncx);              // = p - c  (rn sub per element)
      PK_ADD(dy, py[m], ncy);
      PK_ADD(dz, pz[m], ncz);
      PK_MUL(xx, dx, dx);
      PK_MUL(yy, dy, dy);
      PK_ADD(ss, xx, yy);                  // (dx2+dy2)
      PK_MUL(zz, dz, dz);
      PK_ADD(dd, ss, zz);                  // +dz2 — numpy order, rn each
      float u0 = fminf(d2[m].x, dd.x);
      float u1 = fminf(d2[m].y, dd.y);
      d2[m].x = u0; d2[m].y = u1;
      if (u0 > bv){ bv = u0; bj = 2*m; }   // strict >: keeps lowest local n
      if (u1 > bv){ bv = u1; bj = 2*m+1; }
    }
    int nbest = (tid<<4) + bj;             // global n of this lane's winner
    float mv = wave_max63_f32(bv);
    float mvu = readlane_f32(mv, 63);
    unsigned long long tiedm = __ballot(bv == mvu);
    int wl = __ffsll(tiedm) - 1;           // lowest lane = lowest n
    if (lane == wl)                        // lane wl's bv/nbest ARE the winners
      candK[s&1][wv] = ((unsigned long long)__float_as_uint(bv) << 32)
                     | (unsigned long long)(unsigned)~(unsigned)nbest;
    __syncthreads();
    const ulonglong2* cp = (const ulonglong2*)candK[s&1];
    ulonglong2 c0 = cp[0], c1 = cp[1];
    unsigned long long kk = umax64(umax64(c0.x,c0.y), umax64(c1.x,c1.y));
    far = (int)(~(unsigned)kk) & (NN-1);
    cc = s4[far];
  }
}

__global__ __launch_bounds__(256) void dcen_kernel(const float* __restrict__ density,
    const int* __restrict__ fidx, float* __restrict__ dcen){
  int i = blockIdx.x*256 + threadIdx.x;
  int b = i >> 10;
  dcen[i] = density[(size_t)b*NN + fidx[i]];
}

__global__ __launch_bounds__(256) void dstats_kernel(const float* __restrict__ dcen,
    float* __restrict__ dstat){
  float s=0.f, q=0.f;
  for (int i=threadIdx.x; i<NB*NS; i+=256){ float v=dcen[i]; s+=v; q+=v*v; }
  __shared__ float ls[256], lq[256];
  ls[threadIdx.x]=s; lq[threadIdx.x]=q;
  __syncthreads();
  for (int off=128; off>0; off>>=1){
    if (threadIdx.x<off){ ls[threadIdx.x]+=ls[threadIdx.x+off]; lq[threadIdx.x]+=lq[threadIdx.x+off]; }
    __syncthreads();
  }
  if (threadIdx.x==0){
    float m = ls[0]/(float)(NB*NS);
    dstat[0]=m; dstat[1]=lq[0]/(float)(NB*NS) - m*m;
  }
}

// ---------------------------------------------------------------------------
// kNN (sorted-insert): packed xyz4 {x,y,z,sq}, one b128 load per point.
// Exact (d,n) lex order; neighbor set identical to reference kNN.
// ---------------------------------------------------------------------------
__global__ __launch_bounds__(256) void knn_kernel(const float4* __restrict__ xyz4,
    const float* __restrict__ newxyz, int* __restrict__ kidx){
  const int lane = threadIdx.x & 63;
  const int g = blockIdx.x*4 + (threadIdx.x >> 6);
  const int b = g >> 10;
  const float* cp = newxyz + (size_t)g*3;
  const float cx=cp[0], cy=cp[1], cz=cp[2];
  const float sqc = fadd(fadd(fmul(cx,cx),fmul(cy,cy)),fmul(cz,cz));
  const float4* xb = xyz4 + (size_t)b*NN;
  unsigned long long kept  = ~0ULL;
  unsigned long long worst = ~0ULL;
  for (int n0=0; n0<NN; n0+=64){
    const int n = n0 + lane;
    float4 P = xb[n];
    float dot = fadd(fadd(fmul(cx,P.x),fmul(cy,P.y)),fmul(cz,P.z));
    float d = fsub(fadd(sqc, P.w), fmul(2.0f,dot));
    unsigned u = __float_as_uint(d);
    u = (u & 0x80000000u) ? ~u : (u | 0x80000000u);
    unsigned long long ck = ((unsigned long long)u << 32) | (unsigned)n;
    unsigned long long mask = __ballot(ck < worst);
    while (mask){
      const int l = __ffsll(mask) - 1;
      mask &= mask - 1;
      const unsigned long long k = readlane_u64(ck, l);
      if (k < worst){
        bool m = kept > k;
        unsigned long long M = __ballot(m) << 1;
        unsigned long long sh = wave_shr1_u64(kept);
        bool msh = (M >> lane) & 1ULL;
        unsigned long long ins = msh ? sh : k;
        kept = m ? ins : kept;
        worst = readlane_u64(kept, 31);
      }
    }
  }
  if (lane < 32) kidx[(size_t)g*NK + lane] = (int)(kept & 0xFFFFFFFFULL);
}

// ---------------------------------------------------------------------------
// MFMA convs (layouts verified: A[m=lane&15][k=q*8+j], B same, D
// col=lane&15,row=q*4+reg). LDS rows padded to 72/104 shorts.
// ---------------------------------------------------------------------------

// conv1: 128 pts/block, M=64 outs, K=96 (features k0..63, gxyz k64..66, 0-pad)
__global__ __launch_bounds__(256) void conv1_kernel(const float4* __restrict__ xyz4,
    const unsigned short* __restrict__ ptsT, const float* __restrict__ newxyz,
    const int* __restrict__ kidx, const unsigned short* __restrict__ w0p,
    const float* __restrict__ b0, unsigned short* __restrict__ z1,
    float* __restrict__ partial){
  __shared__ unsigned short sa[128][104];
  __shared__ unsigned short swb[64][104];
  const int tid = threadIdx.x;
  const int p0 = blockIdx.x * 128;
  for (int i = tid; i < 64*64; i += 256){
    int o = i >> 6, c0 = (i & 63)*2;
    if (c0 < 104)
      *(unsigned*)&swb[o][c0] = *(const unsigned*)&w0p[o*128 + c0];
  }
  #pragma unroll
  for (int j=0;j<4;j++){
    int idx = tid + j*256;            // 1024 = 128 pts x 8 groups
    int pt = idx >> 3, cg = idx & 7;
    int p = p0 + pt, g = p >> 5, b = g >> 10;
    int n = kidx[p];
    uint4 vv = *(const uint4*)(ptsT + ((size_t)b*NN + n)*NCF + cg*8);
    *(uint4*)&sa[pt][cg*8] = vv;
  }
  if (tid < 128){
    int p = p0 + tid, g = p >> 5, b = g >> 10;
    int n = kidx[p];
    float4 P = xyz4[(size_t)b*NN + n];
    const float* cp = newxyz + (size_t)g*3;
    float gx = P.x-cp[0], gy = P.y-cp[1], gz = P.z-cp[2];
    *(uint2*)&sa[tid][64] = make_uint2(pack2(gx,gy), pack2(gz,0.f));
    *(uint2*)&sa[tid][68] = make_uint2(0u,0u);
    uint4 zz = make_uint4(0u,0u,0u,0u);
    *(uint4*)&sa[tid][72] = zz; *(uint4*)&sa[tid][80] = zz;
    *(uint4*)&sa[tid][88] = zz; *(uint4*)&sa[tid][96] = zz;
  }
  __syncthreads();
  const int wv = tid >> 6, lane = tid & 63;
  const int r15 = lane & 15, q = lane >> 4;
  f32x4 acc[8];
  #pragma unroll
  for (int t=0;t<8;t++) acc[t] = (f32x4){0.f,0.f,0.f,0.f};
  #pragma unroll
  for (int ks=0; ks<3; ks++){
    bf16x8 af = *(const bf16x8*)&swb[wv*16 + r15][ks*32 + q*8];
    #pragma unroll
    for (int t=0;t<8;t++){
      bf16x8 bfr = *(const bf16x8*)&sa[t*16 + r15][ks*32 + q*8];
      acc[t] = __builtin_amdgcn_mfma_f32_16x16x32_bf16(af, bfr, acc[t], 0,0,0);
    }
  }
  float bias[4];
  #pragma unroll
  for (int r=0;r<4;r++) bias[r] = b0[wv*16 + q*4 + r];
  f2 st[4];
  #pragma unroll
  for (int r=0;r<4;r++) st[r] = (f2){0.f,0.f};
  #pragma unroll
  for (int t=0;t<8;t++){
    float z0=acc[t][0]+bias[0], z1v=acc[t][1]+bias[1];
    float z2v=acc[t][2]+bias[2], z3v=acc[t][3]+bias[3];
    st[0] = pk_add(st[0], (f2){z0, z0*z0});
    st[1] = pk_add(st[1], (f2){z1v, z1v*z1v});
    st[2] = pk_add(st[2], (f2){z2v, z2v*z2v});
    st[3] = pk_add(st[3], (f2){z3v, z3v*z3v});
    *(uint2*)(z1 + (size_t)(p0 + t*16 + r15)*64 + wv*16 + q*4)
        = make_uint2(pack2(z0,z1v), pack2(z2v,z3v));
  }
  #pragma unroll
  for (int r=0;r<4;r++){
    f2 s = row16_sum_f2(st[r]);
    if (r15 == 15){
      int ch = wv*16 + q*4 + r;
      partial[(size_t)blockIdx.x*128 + ch] = s.x;
      partial[(size_t)blockIdx.x*128 + 64 + ch] = s.y;
    }
  }
}

// conv2: 128 pts/block, M=64, K=64; input = relu(scale1*z1+shift1) -> bf16
__global__ __launch_bounds__(256) void conv2_kernel(const unsigned short* __restrict__ z1,
    const unsigned short* __restrict__ w1p, const float* __restrict__ b1,
    const float* __restrict__ scale1, const float* __restrict__ shift1,
    unsigned short* __restrict__ z2, float* __restrict__ partial){
  __shared__ unsigned short sa[128][72];
  __shared__ unsigned short swb[64][72];
  const int tid = threadIdx.x;
  const int p0 = blockIdx.x * 128;
  for (int i = tid; i < 64*32; i += 256){
    int o = i >> 5, c0 = (i & 31)*2;
    *(unsigned*)&swb[o][c0] = *(const unsigned*)&w1p[o*64 + c0];
  }
  #pragma unroll
  for (int j=0;j<4;j++){
    int idx = tid + j*256;
    int pt = idx >> 3, cg = idx & 7;
    uint4 vv = *(const uint4*)(z1 + (size_t)(p0+pt)*64 + cg*8);
    unsigned a[4] = {vv.x, vv.y, vv.z, vv.w};
    unsigned r[4];
    #pragma unroll
    for (int t=0;t<4;t++){
      int c = cg*8 + t*2;
      float lo = __uint_as_float(a[t] << 16);
      float hi = __uint_as_float(a[t] & 0xFFFF0000u);
      float alo = fmaxf(lo*scale1[c]   + shift1[c],   0.f);
      float ahi = fmaxf(hi*scale1[c+1] + shift1[c+1], 0.f);
      r[t] = pack2(alo, ahi);
    }
    *(uint4*)&sa[pt][cg*8] = make_uint4(r[0],r[1],r[2],r[3]);
  }
  __syncthreads();
  const int wv = tid >> 6, lane = tid & 63;
  const int r15 = lane & 15, q = lane >> 4;
  f32x4 acc[8];
  #pragma unroll
  for (int t=0;t<8;t++) acc[t] = (f32x4){0.f,0.f,0.f,0.f};
  #pragma unroll
  for (int ks=0; ks<2; ks++){
    bf16x8 af = *(const bf16x8*)&swb[wv*16 + r15][ks*32 + q*8];
    #pragma unroll
    for (int t=0;t<8;t++){
      bf16x8 bfr = *(const bf16x8*)&sa[t*16 + r15][ks*32 + q*8];
      acc[t] = __builtin_amdgcn_mfma_f32_16x16x32_bf16(af, bfr, acc[t], 0,0,0);
    }
  }
  float bias[4];
  #pragma unroll
  for (int r=0;r<4;r++) bias[r] = b1[wv*16 + q*4 + r];
  f2 st[4];
  #pragma unroll
  for (int r=0;r<4;r++) st[r] = (f2){0.f,0.f};
  #pragma unroll
  for (int t=0;t<8;t++){
    float z0=acc[t][0]+bias[0], z1v=acc[t][1]+bias[1];
    float z2v=acc[t][2]+bias[2], z3v=acc[t][3]+bias[3];
    st[0] = pk_add(st[0], (f2){z0, z0*z0});
    st[1] = pk_add(st[1], (f2){z1v, z1v*z1v});
    st[2] = pk_add(st[2], (f2){z2v, z2v*z2v});
    st[3] = pk_add(st[3], (f2){z3v, z3v*z3v});
    *(uint2*)(z2 + (size_t)(p0 + t*16 + r15)*64 + wv*16 + q*4)
        = make_uint2(pack2(z0,z1v), pack2(z2v,z3v));
  }
  #pragma unroll
  for (int r=0;r<4;r++){
    f2 s = row16_sum_f2(st[r]);
    if (r15 == 15){
      int ch = wv*16 + q*4 + r;
      partial[(size_t)blockIdx.x*128 + ch] = s.x;
      partial[(size_t)blockIdx.x*128 + 64 + ch] = s.y;
    }
  }
}

// conv3: 128 pts (4 centers)/block, M=128, K=64; fused k-max (pre-BN valid);
// m3 written TRANSPOSED [ch][pt] so final_kernel is coalesced.
__global__ __launch_bounds__(256) void conv3_kernel(const unsigned short* __restrict__ z2,
    const unsigned short* __restrict__ w2p, const float* __restrict__ b2,
    const float* __restrict__ scale2, const float* __restrict__ shift2,
    float* __restrict__ m3T, float* __restrict__ partial){
  __shared__ unsigned short sa[128][72];
  __shared__ unsigned short swb[128][72];
  const int tid = threadIdx.x;
  const int p0 = blockIdx.x * 128;
  for (int i = tid; i < 128*32; i += 256){
    int o = i >> 5, c0 = (i & 31)*2;
    *(unsigned*)&swb[o][c0] = *(const unsigned*)&w2p[o*64 + c0];
  }
  #pragma unroll
  for (int j=0;j<4;j++){
    int idx = tid + j*256;
    int pt = idx >> 3, cg = idx & 7;
    uint4 vv = *(const uint4*)(z2 + (size_t)(p0+pt)*64 + cg*8);
    unsigned a[4] = {vv.x, vv.y, vv.z, vv.w};
    unsigned r[4];
    #pragma unroll
    for (int t=0;t<4;t++){
      int c = cg*8 + t*2;
      float lo = __uint_as_float(a[t] << 16);
      float hi = __uint_as_float(a[t] & 0xFFFF0000u);
      float alo = fmaxf(lo*scale2[c]   + shift2[c],   0.f);
      float ahi = fmaxf(hi*scale2[c+1] + shift2[c+1], 0.f);
      r[t] = pack2(alo, ahi);
    }
    *(uint4*)&sa[pt][cg*8] = make_uint4(r[0],r[1],r[2],r[3]);
  }
  __syncthreads();
  const int wv = tid >> 6, lane = tid & 63;
  const int r15 = lane & 15, q = lane >> 4;
  f32x4 acc[2][8];
  #pragma unroll
  for (int mm=0;mm<2;mm++)
    #pragma unroll
    for (int t=0;t<8;t++) acc[mm][t] = (f32x4){0.f,0.f,0.f,0.f};
  #pragma unroll
  for (int ks=0; ks<2; ks++){
    bf16x8 af0 = *(const bf16x8*)&swb[(wv*2+0)*16 + r15][ks*32 + q*8];
    bf16x8 af1 = *(const bf16x8*)&swb[(wv*2+1)*16 + r15][ks*32 + q*8];
    #pragma unroll
    for (int t=0;t<8;t++){
      bf16x8 bfr = *(const bf16x8*)&sa[t*16 + r15][ks*32 + q*8];
      acc[0][t] = __builtin_amdgcn_mfma_f32_16x16x32_bf16(af0, bfr, acc[0][t], 0,0,0);
      acc[1][t] = __builtin_amdgcn_mfma_f32_16x16x32_bf16(af1, bfr, acc[1][t], 0,0,0);
    }
  }
  #pragma unroll
  for (int mm=0;mm<2;mm++){
    const int base = (wv*2+mm)*16;
    float bias[4];
    #pragma unroll
    for (int r=0;r<4;r++) bias[r] = b2[base + q*4 + r];
    float zv[8][4];
    f2 st[4];
    #pragma unroll
    for (int r=0;r<4;r++) st[r] = (f2){0.f,0.f};
    #pragma unroll
    for (int t=0;t<8;t++){
      #pragma unroll
      for (int r=0;r<4;r++){
        float z = acc[mm][t][r] + bias[r];
        zv[t][r] = z;
        st[r] = pk_add(st[r], (f2){z, z*z});
      }
    }
    #pragma unroll
    for (int r=0;r<4;r++){
      f2 s = row16_sum_f2(st[r]);
      if (r15 == 15){
        int ch = base + q*4 + r;
        partial[(size_t)blockIdx.x*256 + ch] = s.x;
        partial[(size_t)blockIdx.x*256 + 128 + ch] = s.y;
      }
    }
    #pragma unroll
    for (int c=0;c<4;c++){
      #pragma unroll
      for (int r=0;r<4;r++){
        float m = row16_max_f32(fmaxf(zv[2*c][r], zv[2*c+1][r]));
        if (r15 == 15)
          m3T[(size_t)(base + q*4 + r)*(NB*NS) + blockIdx.x*4 + c] = m;
      }
    }
  }
}

// reduce per-block partials -> BN scale/shift per channel
__global__ __launch_bounds__(256) void mkbn_kernel(const float* __restrict__ partial,
    int nrows, int stride, const float* __restrict__ g, const float* __restrict__ be,
    float* __restrict__ scale, float* __restrict__ shift, float inv_count){
  const int c = blockIdx.x;
  const int C = gridDim.x;
  float s=0.f, q=0.f;
  for (int r=threadIdx.x; r<nrows; r+=256){
    s += partial[(size_t)r*stride + c];
    q += partial[(size_t)r*stride + C + c];
  }
  __shared__ float ls[256], lq[256];
  ls[threadIdx.x]=s; lq[threadIdx.x]=q;
  __syncthreads();
  for (int off=128; off>0; off>>=1){
    if (threadIdx.x < off){ ls[threadIdx.x]+=ls[threadIdx.x+off]; lq[threadIdx.x]+=lq[threadIdx.x+off]; }
    __syncthreads();
  }
  if (threadIdx.x==0){
    float mean = ls[0]*inv_count;
    float var  = lq[0]*inv_count - mean*mean;
    float sc = g[c]*rsqrtf(var + EPSV);
    scale[c]=sc; shift[c]=be[c]-mean*sc;
  }
}

// out[b,ch,s] = relu(scale3*maxz + shift3) * relu(bn_d(wd*dcen+bd))
// vectorized x4 along s; m3T [ch][b*1024+s] -> coalesced b128 both sides.
__global__ __launch_bounds__(256) void final_kernel(const float* __restrict__ m3T,
    const float* __restrict__ dcen, const float* __restrict__ scale3,
    const float* __restrict__ shift3, const float* __restrict__ wd,
    const float* __restrict__ bd, const float* __restrict__ gd,
    const float* __restrict__ bed, const float* __restrict__ dstat,
    float* __restrict__ out){
  int t = blockIdx.x*256 + threadIdx.x;   // 524288 threads x 4 elems
  int s0 = (t & 255) * 4;
  int ch = (t >> 8) & 127;
  int b  = t >> 15;
  float mean_d = dstat[0], var_d = dstat[1];
  float w = wd[ch];
  float meanp = w*mean_d + bd[ch];
  float varp  = w*w*var_d;
  float dsc = gd[ch]*rsqrtf(varp + EPSV);
  float dsh = bed[ch] - meanp*dsc;
  float sc3 = scale3[ch], sh3 = shift3[ch];
  float4 dc = *(const float4*)&dcen[b*NS + s0];
  float4 zv = *(const float4*)&m3T[(size_t)ch*(NB*NS) + b*NS + s0];
  float4 o;
  o.x = fmaxf(sc3*zv.x + sh3, 0.f) * fmaxf(dsc*(w*dc.x + bd[ch]) + dsh, 0.f);
  o.y = fmaxf(sc3*zv.y + sh3, 0.f) * fmaxf(dsc*(w*dc.y + bd[ch]) + dsh, 0.f);
  o.z = fmaxf(sc3*zv.z + sh3, 0.f) * fmaxf(dsc*(w*dc.z + bd[ch]) + dsh, 0.f);
  o.w = fmaxf(sc3*zv.w + sh3, 0.f) * fmaxf(dsc*(w*dc.w + bd[ch]) + dsh, 0.f);
  *(float4*)&out[(size_t)t*4] = o;
}

// ---------------------------------------------------------------------------
extern "C" void kernel_launch(void* const* d_in, const int* in_sizes, int n_in,
                              void* d_out, int out_size, void* d_ws, size_t ws_size,
                              hipStream_t stream){
  const float* xyz     = (const float*)d_in[0];
  const float* points  = (const float*)d_in[1];
  const float* density = (const float*)d_in[2];
  const float* w0 = (const float*)d_in[3];
  const float* b0 = (const float*)d_in[4];
  const float* g0 = (const float*)d_in[5];
  const float* be0= (const float*)d_in[6];
  const float* w1 = (const float*)d_in[7];
  const float* b1 = (const float*)d_in[8];
  const float* g1 = (const float*)d_in[9];
  const float* be1= (const float*)d_in[10];
  const float* w2 = (const float*)d_in[11];
  const float* b2 = (const float*)d_in[12];
  const float* g2 = (const float*)d_in[13];
  const float* be2= (const float*)d_in[14];
  const float* wd = (const float*)d_in[15];
  const float* bd = (const float*)d_in[16];
  const float* gd = (const float*)d_in[17];
  const float* bed= (const float*)d_in[18];

  float* out = (float*)d_out;
  float* newxyz = out;                 // (B,S,3) = output 0
  float* out1   = out + (size_t)NB*NS*3;

  // workspace layout
  unsigned short* ptsT = (unsigned short*)d_ws;          // 4,194,304 u16
  float4* xyz4 = (float4*)(ptsT + (size_t)NB*NN*NCF);    // 65,536 float4
  int*   fidx = (int*)(xyz4 + (size_t)NB*NN);            // 16,384 i
  float* dcen = (float*)(fidx + NB*NS);                  // 16,384 f
  int*   kidx = (int*)(dcen + NB*NS);                    // 524,288 i
  unsigned short* z1 = (unsigned short*)(kidx + NPTS);   // 33,554,432 u16
  unsigned short* z2 = z1 + (size_t)NPTS*64;             // 33,554,432 u16
  float* m3T  = (float*)(z2 + (size_t)NPTS*64);          // 2,097,152 f
  float* p1   = m3T + (size_t)NB*NS*128;                 // 4096*128 f
  float* p2   = p1 + 4096*128;                           // 4096*128 f
  float* p3   = p2 + 4096*128;                           // 4096*256 f
  float* bnp  = p3 + 4096*256;                           // 512 f
  float* dstat= bnp + 512;                               // 2 f
  unsigned short* w0p = (unsigned short*)(dstat + 2);    // 8192 u16
  unsigned short* w1p = w0p + 64*128;                    // 4096 u16
  unsigned short* w2p = w1p + 64*64;                     // 8192 u16

  hipLaunchKernelGGL(prep_kernel,  dim3(256),  dim3(256), 0, stream, points, xyz, ptsT, xyz4,
                     w0, w1, w2, w0p, w1p, w2p);
  hipLaunchKernelGGL(fps_kernel,   dim3(NB),   dim3(FT),  0, stream, xyz4, fidx, newxyz);
  hipLaunchKernelGGL(dcen_kernel,  dim3(64),   dim3(256), 0, stream, density, fidx, dcen);
  hipLaunchKernelGGL(dstats_kernel,dim3(1),    dim3(256), 0, stream, dcen, dstat);
  hipLaunchKernelGGL(knn_kernel,   dim3(4096), dim3(256), 0, stream, xyz4, newxyz, kidx);
  hipLaunchKernelGGL(conv1_kernel, dim3(4096), dim3(256), 0, stream, xyz4, ptsT, newxyz, kidx, w0p, b0, z1, p1);
  hipLaunchKernelGGL(mkbn_kernel,  dim3(64),   dim3(256), 0, stream, p1, 4096, 128, g0, be0, bnp+0,   bnp+64,  1.0f/(float)NPTS);
  hipLaunchKernelGGL(conv2_kernel, dim3(4096), dim3(256), 0, stream, z1, w1p, b1, bnp+0, bnp+64, z2, p2);
  hipLaunchKernelGGL(mkbn_kernel,  dim3(64),   dim3(256), 0, stream, p2, 4096, 128, g1, be1, bnp+128, bnp+192, 1.0f/(float)NPTS);
  hipLaunchKernelGGL(conv3_kernel, dim3(4096), dim3(256), 0, stream, z2, w2p, b2, bnp+128, bnp+192, m3T, p3);
  hipLaunchKernelGGL(mkbn_kernel,  dim3(128),  dim3(256), 0, stream, p3, 4096, 256, g2, be2, bnp+256, bnp+384, 1.0f/(float)NPTS);
  hipLaunchKernelGGL(final_kernel, dim3(2048), dim3(256), 0, stream, m3T, dcen, bnp+256, bnp+384, wd, bd, gd, bed, dstat, out1);
}

// Round 11
// 1086.582 us; speedup vs baseline: 1.0142x; 1.0142x over previous
//
#include <hip/hip_runtime.h>
#include <hip/hip_bf16.h>
#include <stdint.h>

// Problem constants (fixed by the reference)
#define NB 16
#define NN 4096
#define NCF 64
#define NS 1024
#define NK 32
#define NPTS (NB*NS*NK)   // 524288
#define CIN 67
#define EPSV 1e-5f

// rn intrinsics: block FMA contraction so FPS/kNN distances bit-match numpy
static __device__ __forceinline__ float fmul(float a, float b){ return __fmul_rn(a,b); }
static __device__ __forceinline__ float fadd(float a, float b){ return __fadd_rn(a,b); }
static __device__ __forceinline__ float fsub(float a, float b){ return __fsub_rn(a,b); }

typedef float f2 __attribute__((ext_vector_type(2)));
#define PK_ADD(d,a,b) asm("v_pk_add_f32 %0, %1, %2" : "=v"(d) : "v"(a), "v"(b))
#define PK_MUL(d,a,b) asm("v_pk_mul_f32 %0, %1, %2" : "=v"(d) : "v"(a), "v"(b))
static __device__ __forceinline__ f2 pk_add(f2 a, f2 b){ f2 d; PK_ADD(d,a,b); return d; }

// MFMA fragment types (gfx950 16x16x32 bf16: 8 bf16 in / 4 f32 acc per lane)
typedef short bf16x8 __attribute__((ext_vector_type(8)));
typedef float f32x4 __attribute__((ext_vector_type(4)));

static __device__ __forceinline__ unsigned short f2b(float f){
  unsigned u = __float_as_uint(f);
  return (unsigned short)((u + 0x7FFFu + ((u>>16)&1u)) >> 16);  // RNE bf16
}
static __device__ __forceinline__ unsigned pack2(float a, float b){
  return (unsigned)f2b(a) | ((unsigned)f2b(b)<<16);
}
static __device__ __forceinline__ float readlane_f32(float v, int l){
  return __uint_as_float((unsigned)__builtin_amdgcn_readlane((int)__float_as_uint(v), l));
}

// ---- DPP cross-lane reductions (pure VALU) ---------------------------------
template<int CTRL>
static __device__ __forceinline__ float dppmax_f32(float x){   // 0-fill (x>=0 only)
  float o = __uint_as_float((unsigned)__builtin_amdgcn_update_dpp(
      0, (int)__float_as_uint(x), CTRL, 0xf, 0xf, true));
  return fmaxf(x, o);
}
static __device__ __forceinline__ float wave_max63_f32(float x){
  x = dppmax_f32<0x111>(x); x = dppmax_f32<0x112>(x);
  x = dppmax_f32<0x114>(x); x = dppmax_f32<0x118>(x);
  x = dppmax_f32<0x142>(x); x = dppmax_f32<0x143>(x);
  return x;
}
// row-16 max keeping own value on invalid lanes (safe for negatives)
template<int CTRL>
static __device__ __forceinline__ float dppmax_keep(float x){
  float o = __uint_as_float((unsigned)__builtin_amdgcn_update_dpp(
      (int)__float_as_uint(x), (int)__float_as_uint(x), CTRL, 0xf, 0xf, false));
  return fmaxf(x, o);
}
static __device__ __forceinline__ float row16_max_f32(float x){
  x = dppmax_keep<0x111>(x); x = dppmax_keep<0x112>(x);
  x = dppmax_keep<0x114>(x); x = dppmax_keep<0x118>(x);
  return x;
}
template<int CTRL>
static __device__ __forceinline__ f2 dppadd_f2(f2 x){
  f2 o;
  o.x = __uint_as_float((unsigned)__builtin_amdgcn_update_dpp(
      0, (int)__float_as_uint(x.x), CTRL, 0xf, 0xf, true));
  o.y = __uint_as_float((unsigned)__builtin_amdgcn_update_dpp(
      0, (int)__float_as_uint(x.y), CTRL, 0xf, 0xf, true));
  return pk_add(x, o);
}
// row-16 sum -> valid in lane (row*16+15)
static __device__ __forceinline__ f2 row16_sum_f2(f2 x){
  x = dppadd_f2<0x111>(x); x = dppadd_f2<0x112>(x);
  x = dppadd_f2<0x114>(x); x = dppadd_f2<0x118>(x);
  return x;
}
static __device__ __forceinline__ unsigned long long readlane_u64(unsigned long long v, int l){
  unsigned lo = (unsigned)__builtin_amdgcn_readlane((int)(unsigned)v, l);
  unsigned hi = (unsigned)__builtin_amdgcn_readlane((int)(unsigned)(v>>32), l);
  return ((unsigned long long)hi<<32) | lo;
}
static __device__ __forceinline__ unsigned long long wave_shr1_u64(unsigned long long x){
  unsigned lo = (unsigned)__builtin_amdgcn_update_dpp(
      0, (int)(unsigned)x, 0x138, 0xf, 0xf, true);
  unsigned hi = (unsigned)__builtin_amdgcn_update_dpp(
      0, (int)(unsigned)(x>>32), 0x138, 0xf, 0xf, true);
  return ((unsigned long long)hi<<32) | lo;
}
static __device__ __forceinline__ unsigned long long umax64(unsigned long long a,
                                                            unsigned long long b){
  return a > b ? a : b;
}

// ---------------------------------------------------------------------------
// prep: transpose points (B,CF,N)->(B,N,CF) as BF16, pack xyz4={x,y,z,sq};
// block 0 additionally converts/pads the conv weights to bf16 (folded wprep).
// ---------------------------------------------------------------------------
__global__ __launch_bounds__(256) void prep_kernel(const float* __restrict__ pts,
    const float* __restrict__ xyz, unsigned short* __restrict__ ptsT,
    float4* __restrict__ xyz4,
    const float* __restrict__ w0, const float* __restrict__ w1,
    const float* __restrict__ w2, unsigned short* __restrict__ w0p,
    unsigned short* __restrict__ w1p, unsigned short* __restrict__ w2p){
  int blk = blockIdx.x;            // 256 blocks = 16 b * 16 chunks
  int b = blk >> 4;
  int n = ((blk & 15) << 8) + threadIdx.x;
  const float* src = pts + (size_t)b*NCF*NN + n;
  float v[NCF];
  #pragma unroll
  for (int c=0;c<NCF;c++) v[c] = src[(size_t)c*NN];
  uint4* dst = (uint4*)(ptsT + ((size_t)b*NN + n)*NCF);
  #pragma unroll
  for (int j=0;j<8;j++)
    dst[j] = make_uint4(pack2(v[8*j],v[8*j+1]), pack2(v[8*j+2],v[8*j+3]),
                        pack2(v[8*j+4],v[8*j+5]), pack2(v[8*j+6],v[8*j+7]));
  const float* xp = xyz + ((size_t)b*NN + n)*3;
  float x=xp[0], y=xp[1], z=xp[2];
  float sq = fadd(fadd(fmul(x,x),fmul(y,y)),fmul(z,z));
  xyz4[(size_t)b*NN+n] = make_float4(x,y,z,sq);
  if (blk == 0){
    const int tid = threadIdx.x;
    for (int i = tid; i < 64*128; i += 256){
      int o = i >> 7, c = i & 127;
      float vv = 0.f;
      if (c < 64) vv = w0[o*CIN + 3 + c];        // features -> k0..63
      else if (c < 67) vv = w0[o*CIN + (c-64)];  // gxyz -> k64..66
      w0p[i] = f2b(vv);
    }
    for (int i = tid; i < 64*64; i += 256)  w1p[i] = f2b(w1[i]);
    for (int i = tid; i < 128*64; i += 256) w2p[i] = f2b(w2[i]);
  }
}

// ---------------------------------------------------------------------------
// FPS — R9-measured-best (619 us): one block per batch, 256 threads (4
// waves), CONTIGUOUS ownership [16t,16t+16) -> lane order == n order. Per
// step: packed rn distance update -> (bv,bj) strict > -> DPP f32 max ->
// readlane(63) -> ballot tie -> lowest lane -> readlane(n) -> UNIFORM leader
// write ((tid&63)==0) of u64 key to parity slot -> 1 barrier -> b128 read of
// 4 keys + 3 umax -> s4[far]. np.argmax exact (max value, tie->lowest index).
// Measured-worse variants: divergent lane-wl write (R10 645), payload carry
// via LDS (R5 669) or registers (R7 829), 512 thr (R6 648), u64 butterflies
// (R2/R3 904/821).
// ---------------------------------------------------------------------------
#define FT 256
__global__ __launch_bounds__(FT) void fps_kernel(const float4* __restrict__ xyz4,
    int* __restrict__ fidx, float* __restrict__ newxyz){
  int b = blockIdx.x;
  __shared__ float4 s4[NN];                       // 64 KB {x,y,z,sq}
  __shared__ unsigned long long candK[2][4];      // parity-double-buffered keys
  const int tid = threadIdx.x;
  for (int i = tid; i < NN; i += FT)
    s4[i] = xyz4[(size_t)b*NN + i];
  __syncthreads();
  // pair m: .x -> n = 16*tid + 2m, .y -> n = 16*tid + 2m + 1 (ascending)
  f2 px[8], py[8], pz[8], d2[8];
  #pragma unroll
  for (int m=0;m<8;m++){
    float4 a = s4[tid*16 + 2*m];
    float4 c = s4[tid*16 + 2*m + 1];
    px[m] = (f2){a.x, c.x};
    py[m] = (f2){a.y, c.y};
    pz[m] = (f2){a.z, c.z};
    d2[m] = (f2){1e10f, 1e10f};
  }
  int far = 0;
  float4 cc = s4[0];
  for (int s=0;s<NS;s++){
    if (tid==0){
      fidx[b*NS+s] = far;
      float* o = newxyz + ((size_t)b*NS+s)*3;
      o[0]=cc.x; o[1]=cc.y; o[2]=cc.z;
    }
    f2 ncx = (f2){-cc.x,-cc.x}, ncy = (f2){-cc.y,-cc.y}, ncz = (f2){-cc.z,-cc.z};
    float bv = -1.0f; int bj = 0;
    #pragma unroll
    for (int m=0;m<8;m++){
      f2 dx,dy,dz,xx,yy,zz,ss,dd;
      PK_ADD(dx, px[m], ncx);              // = p - c  (rn sub per element)
      PK_ADD(dy, py[m], ncy);
      PK_ADD(dz, pz[m], ncz);
      PK_MUL(xx, dx, dx);
      PK_MUL(yy, dy, dy);
      PK_ADD(ss, xx, yy);                  // (dx2+dy2)
      PK_MUL(zz, dz, dz);
      PK_ADD(dd, ss, zz);                  // +dz2 — numpy order, rn each
      float u0 = fminf(d2[m].x, dd.x);
      float u1 = fminf(d2[m].y, dd.y);
      d2[m].x = u0; d2[m].y = u1;
      if (u0 > bv){ bv = u0; bj = 2*m; }   // strict >: keeps lowest local n
      if (u1 > bv){ bv = u1; bj = 2*m+1; }
    }
    int nbest = (tid<<4) + bj;             // global n of this lane's winner
    float mv = wave_max63_f32(bv);
    float mvu = readlane_f32(mv, 63);
    unsigned long long tiedm = __ballot(bv == mvu);
    int wl = __ffsll(tiedm) - 1;           // lowest lane = lowest n
    unsigned nwin = (unsigned)__builtin_amdgcn_readlane(nbest, wl);
    if ((tid & 63) == 0)
      candK[s&1][tid>>6] = ((unsigned long long)__float_as_uint(mvu) << 32)
                         | (unsigned long long)(unsigned)~nwin;
    __syncthreads();
    const ulonglong2* cp = (const ulonglong2*)candK[s&1];
    ulonglong2 c0 = cp[0], c1 = cp[1];
    unsigned long long kk = umax64(umax64(c0.x,c0.y), umax64(c1.x,c1.y));
    far = (int)(~(unsigned)kk) & (NN-1);
    cc = s4[far];
  }
}

__global__ __launch_bounds__(256) void dcen_kernel(const float* __restrict__ density,
    const int* __restrict__ fidx, float* __restrict__ dcen){
  int i = blockIdx.x*256 + threadIdx.x;
  int b = i >> 10;
  dcen[i] = density[(size_t)b*NN + fidx[i]];
}

__global__ __launch_bounds__(256) void dstats_kernel(const float* __restrict__ dcen,
    float* __restrict__ dstat){
  float s=0.f, q=0.f;
  for (int i=threadIdx.x; i<NB*NS; i+=256){ float v=dcen[i]; s+=v; q+=v*v; }
  __shared__ float ls[256], lq[256];
  ls[threadIdx.x]=s; lq[threadIdx.x]=q;
  __syncthreads();
  for (int off=128; off>0; off>>=1){
    if (threadIdx.x<off){ ls[threadIdx.x]+=ls[threadIdx.x+off]; lq[threadIdx.x]+=lq[threadIdx.x+off]; }
    __syncthreads();
  }
  if (threadIdx.x==0){
    float m = ls[0]/(float)(NB*NS);
    dstat[0]=m; dstat[1]=lq[0]/(float)(NB*NS) - m*m;
  }
}

// ---------------------------------------------------------------------------
// kNN (sorted-insert): packed xyz4 {x,y,z,sq}, one b128 load per point.
// Exact (d,n) lex order; neighbor set identical to reference kNN.
// ---------------------------------------------------------------------------
__global__ __launch_bounds__(256) void knn_kernel(const float4* __restrict__ xyz4,
    const float* __restrict__ newxyz, int* __restrict__ kidx){
  const int lane = threadIdx.x & 63;
  const int g = blockIdx.x*4 + (threadIdx.x >> 6);
  const int b = g >> 10;
  const float* cp = newxyz + (size_t)g*3;
  const float cx=cp[0], cy=cp[1], cz=cp[2];
  const float sqc = fadd(fadd(fmul(cx,cx),fmul(cy,cy)),fmul(cz,cz));
  const float4* xb = xyz4 + (size_t)b*NN;
  unsigned long long kept  = ~0ULL;
  unsigned long long worst = ~0ULL;
  for (int n0=0; n0<NN; n0+=64){
    const int n = n0 + lane;
    float4 P = xb[n];
    float dot = fadd(fadd(fmul(cx,P.x),fmul(cy,P.y)),fmul(cz,P.z));
    float d = fsub(fadd(sqc, P.w), fmul(2.0f,dot));
    unsigned u = __float_as_uint(d);
    u = (u & 0x80000000u) ? ~u : (u | 0x80000000u);
    unsigned long long ck = ((unsigned long long)u << 32) | (unsigned)n;
    unsigned long long mask = __ballot(ck < worst);
    while (mask){
      const int l = __ffsll(mask) - 1;
      mask &= mask - 1;
      const unsigned long long k = readlane_u64(ck, l);
      if (k < worst){
        bool m = kept > k;
        unsigned long long M = __ballot(m) << 1;
        unsigned long long sh = wave_shr1_u64(kept);
        bool msh = (M >> lane) & 1ULL;
        unsigned long long ins = msh ? sh : k;
        kept = m ? ins : kept;
        worst = readlane_u64(kept, 31);
      }
    }
  }
  if (lane < 32) kidx[(size_t)g*NK + lane] = (int)(kept & 0xFFFFFFFFULL);
}

// ---------------------------------------------------------------------------
// MFMA convs (layouts verified: A[m=lane&15][k=q*8+j], B same, D
// col=lane&15,row=q*4+reg). LDS rows padded to 72/104 shorts.
// ---------------------------------------------------------------------------

// conv1: 128 pts/block, M=64 outs, K=96 (features k0..63, gxyz k64..66, 0-pad)
__global__ __launch_bounds__(256) void conv1_kernel(const float4* __restrict__ xyz4,
    const unsigned short* __restrict__ ptsT, const float* __restrict__ newxyz,
    const int* __restrict__ kidx, const unsigned short* __restrict__ w0p,
    const float* __restrict__ b0, unsigned short* __restrict__ z1,
    float* __restrict__ partial){
  __shared__ unsigned short sa[128][104];
  __shared__ unsigned short swb[64][104];
  const int tid = threadIdx.x;
  const int p0 = blockIdx.x * 128;
  for (int i = tid; i < 64*64; i += 256){
    int o = i >> 6, c0 = (i & 63)*2;
    if (c0 < 104)
      *(unsigned*)&swb[o][c0] = *(const unsigned*)&w0p[o*128 + c0];
  }
  #pragma unroll
  for (int j=0;j<4;j++){
    int idx = tid + j*256;            // 1024 = 128 pts x 8 groups
    int pt = idx >> 3, cg = idx & 7;
    int p = p0 + pt, g = p >> 5, b = g >> 10;
    int n = kidx[p];
    uint4 vv = *(const uint4*)(ptsT + ((size_t)b*NN + n)*NCF + cg*8);
    *(uint4*)&sa[pt][cg*8] = vv;
  }
  if (tid < 128){
    int p = p0 + tid, g = p >> 5, b = g >> 10;
    int n = kidx[p];
    float4 P = xyz4[(size_t)b*NN + n];
    const float* cp = newxyz + (size_t)g*3;
    float gx = P.x-cp[0], gy = P.y-cp[1], gz = P.z-cp[2];
    *(uint2*)&sa[tid][64] = make_uint2(pack2(gx,gy), pack2(gz,0.f));
    *(uint2*)&sa[tid][68] = make_uint2(0u,0u);
    uint4 zz = make_uint4(0u,0u,0u,0u);
    *(uint4*)&sa[tid][72] = zz; *(uint4*)&sa[tid][80] = zz;
    *(uint4*)&sa[tid][88] = zz; *(uint4*)&sa[tid][96] = zz;
  }
  __syncthreads();
  const int wv = tid >> 6, lane = tid & 63;
  const int r15 = lane & 15, q = lane >> 4;
  f32x4 acc[8];
  #pragma unroll
  for (int t=0;t<8;t++) acc[t] = (f32x4){0.f,0.f,0.f,0.f};
  #pragma unroll
  for (int ks=0; ks<3; ks++){
    bf16x8 af = *(const bf16x8*)&swb[wv*16 + r15][ks*32 + q*8];
    #pragma unroll
    for (int t=0;t<8;t++){
      bf16x8 bfr = *(const bf16x8*)&sa[t*16 + r15][ks*32 + q*8];
      acc[t] = __builtin_amdgcn_mfma_f32_16x16x32_bf16(af, bfr, acc[t], 0,0,0);
    }
  }
  float bias[4];
  #pragma unroll
  for (int r=0;r<4;r++) bias[r] = b0[wv*16 + q*4 + r];
  f2 st[4];
  #pragma unroll
  for (int r=0;r<4;r++) st[r] = (f2){0.f,0.f};
  #pragma unroll
  for (int t=0;t<8;t++){
    float z0=acc[t][0]+bias[0], z1v=acc[t][1]+bias[1];
    float z2v=acc[t][2]+bias[2], z3v=acc[t][3]+bias[3];
    st[0] = pk_add(st[0], (f2){z0, z0*z0});
    st[1] = pk_add(st[1], (f2){z1v, z1v*z1v});
    st[2] = pk_add(st[2], (f2){z2v, z2v*z2v});
    st[3] = pk_add(st[3], (f2){z3v, z3v*z3v});
    *(uint2*)(z1 + (size_t)(p0 + t*16 + r15)*64 + wv*16 + q*4)
        = make_uint2(pack2(z0,z1v), pack2(z2v,z3v));
  }
  #pragma unroll
  for (int r=0;r<4;r++){
    f2 s = row16_sum_f2(st[r]);
    if (r15 == 15){
      int ch = wv*16 + q*4 + r;
      partial[(size_t)blockIdx.x*128 + ch] = s.x;
      partial[(size_t)blockIdx.x*128 + 64 + ch] = s.y;
    }
  }
}

// conv2: 128 pts/block, M=64, K=64; input = relu(scale1*z1+shift1) -> bf16
__global__ __launch_bounds__(256) void conv2_kernel(const unsigned short* __restrict__ z1,
    const unsigned short* __restrict__ w1p, const float* __restrict__ b1,
    const float* __restrict__ scale1, const float* __restrict__ shift1,
    unsigned short* __restrict__ z2, float* __restrict__ partial){
  __shared__ unsigned short sa[128][72];
  __shared__ unsigned short swb[64][72];
  const int tid = threadIdx.x;
  const int p0 = blockIdx.x * 128;
  for (int i = tid; i < 64*32; i += 256){
    int o = i >> 5, c0 = (i & 31)*2;
    *(unsigned*)&swb[o][c0] = *(const unsigned*)&w1p[o*64 + c0];
  }
  #pragma unroll
  for (int j=0;j<4;j++){
    int idx = tid + j*256;
    int pt = idx >> 3, cg = idx & 7;
    uint4 vv = *(const uint4*)(z1 + (size_t)(p0+pt)*64 + cg*8);
    unsigned a[4] = {vv.x, vv.y, vv.z, vv.w};
    unsigned r[4];
    #pragma unroll
    for (int t=0;t<4;t++){
      int c = cg*8 + t*2;
      float lo = __uint_as_float(a[t] << 16);
      float hi = __uint_as_float(a[t] & 0xFFFF0000u);
      float alo = fmaxf(lo*scale1[c]   + shift1[c],   0.f);
      float ahi = fmaxf(hi*scale1[c+1] + shift1[c+1], 0.f);
      r[t] = pack2(alo, ahi);
    }
    *(uint4*)&sa[pt][cg*8] = make_uint4(r[0],r[1],r[2],r[3]);
  }
  __syncthreads();
  const int wv = tid >> 6, lane = tid & 63;
  const int r15 = lane & 15, q = lane >> 4;
  f32x4 acc[8];
  #pragma unroll
  for (int t=0;t<8;t++) acc[t] = (f32x4){0.f,0.f,0.f,0.f};
  #pragma unroll
  for (int ks=0; ks<2; ks++){
    bf16x8 af = *(const bf16x8*)&swb[wv*16 + r15][ks*32 + q*8];
    #pragma unroll
    for (int t=0;t<8;t++){
      bf16x8 bfr = *(const bf16x8*)&sa[t*16 + r15][ks*32 + q*8];
      acc[t] = __builtin_amdgcn_mfma_f32_16x16x32_bf16(af, bfr, acc[t], 0,0,0);
    }
  }
  float bias[4];
  #pragma unroll
  for (int r=0;r<4;r++) bias[r] = b1[wv*16 + q*4 + r];
  f2 st[4];
  #pragma unroll
  for (int r=0;r<4;r++) st[r] = (f2){0.f,0.f};
  #pragma unroll
  for (int t=0;t<8;t++){
    float z0=acc[t][0]+bias[0], z1v=acc[t][1]+bias[1];
    float z2v=acc[t][2]+bias[2], z3v=acc[t][3]+bias[3];
    st[0] = pk_add(st[0], (f2){z0, z0*z0});
    st[1] = pk_add(st[1], (f2){z1v, z1v*z1v});
    st[2] = pk_add(st[2], (f2){z2v, z2v*z2v});
    st[3] = pk_add(st[3], (f2){z3v, z3v*z3v});
    *(uint2*)(z2 + (size_t)(p0 + t*16 + r15)*64 + wv*16 + q*4)
        = make_uint2(pack2(z0,z1v), pack2(z2v,z3v));
  }
  #pragma unroll
  for (int r=0;r<4;r++){
    f2 s = row16_sum_f2(st[r]);
    if (r15 == 15){
      int ch = wv*16 + q*4 + r;
      partial[(size_t)blockIdx.x*128 + ch] = s.x;
      partial[(size_t)blockIdx.x*128 + 64 + ch] = s.y;
    }
  }
}

// conv3: 128 pts (4 centers)/block, M=128, K=64; fused k-max (pre-BN valid);
// m3 written TRANSPOSED [ch][pt] so final_kernel is coalesced.
__global__ __launch_bounds__(256) void conv3_kernel(const unsigned short* __restrict__ z2,
    const unsigned short* __restrict__ w2p, const float* __restrict__ b2,
    const float* __restrict__ scale2, const float* __restrict__ shift2,
    float* __restrict__ m3T, float* __restrict__ partial){
  __shared__ unsigned short sa[128][72];
  __shared__ unsigned short swb[128][72];
  const int tid = threadIdx.x;
  const int p0 = blockIdx.x * 128;
  for (int i = tid; i < 128*32; i += 256){
    int o = i >> 5, c0 = (i & 31)*2;
    *(unsigned*)&swb[o][c0] = *(const unsigned*)&w2p[o*64 + c0];
  }
  #pragma unroll
  for (int j=0;j<4;j++){
    int idx = tid + j*256;
    int pt = idx >> 3, cg = idx & 7;
    uint4 vv = *(const uint4*)(z2 + (size_t)(p0+pt)*64 + cg*8);
    unsigned a[4] = {vv.x, vv.y, vv.z, vv.w};
    unsigned r[4];
    #pragma unroll
    for (int t=0;t<4;t++){
      int c = cg*8 + t*2;
      float lo = __uint_as_float(a[t] << 16);
      float hi = __uint_as_float(a[t] & 0xFFFF0000u);
      float alo = fmaxf(lo*scale2[c]   + shift2[c],   0.f);
      float ahi = fmaxf(hi*scale2[c+1] + shift2[c+1], 0.f);
      r[t] = pack2(alo, ahi);
    }
    *(uint4*)&sa[pt][cg*8] = make_uint4(r[0],r[1],r[2],r[3]);
  }
  __syncthreads();
  const int wv = tid >> 6, lane = tid & 63;
  const int r15 = lane & 15, q = lane >> 4;
  f32x4 acc[2][8];
  #pragma unroll
  for (int mm=0;mm<2;mm++)
    #pragma unroll
    for (int t=0;t<8;t++) acc[mm][t] = (f32x4){0.f,0.f,0.f,0.f};
  #pragma unroll
  for (int ks=0; ks<2; ks++){
    bf16x8 af0 = *(const bf16x8*)&swb[(wv*2+0)*16 + r15][ks*32 + q*8];
    bf16x8 af1 = *(const bf16x8*)&swb[(wv*2+1)*16 + r15][ks*32 + q*8];
    #pragma unroll
    for (int t=0;t<8;t++){
      bf16x8 bfr = *(const bf16x8*)&sa[t*16 + r15][ks*32 + q*8];
      acc[0][t] = __builtin_amdgcn_mfma_f32_16x16x32_bf16(af0, bfr, acc[0][t], 0,0,0);
      acc[1][t] = __builtin_amdgcn_mfma_f32_16x16x32_bf16(af1, bfr, acc[1][t], 0,0,0);
    }
  }
  #pragma unroll
  for (int mm=0;mm<2;mm++){
    const int base = (wv*2+mm)*16;
    float bias[4];
    #pragma unroll
    for (int r=0;r<4;r++) bias[r] = b2[base + q*4 + r];
    float zv[8][4];
    f2 st[4];
    #pragma unroll
    for (int r=0;r<4;r++) st[r] = (f2){0.f,0.f};
    #pragma unroll
    for (int t=0;t<8;t++){
      #pragma unroll
      for (int r=0;r<4;r++){
        float z = acc[mm][t][r] + bias[r];
        zv[t][r] = z;
        st[r] = pk_add(st[r], (f2){z, z*z});
      }
    }
    #pragma unroll
    for (int r=0;r<4;r++){
      f2 s = row16_sum_f2(st[r]);
      if (r15 == 15){
        int ch = base + q*4 + r;
        partial[(size_t)blockIdx.x*256 + ch] = s.x;
        partial[(size_t)blockIdx.x*256 + 128 + ch] = s.y;
      }
    }
    #pragma unroll
    for (int c=0;c<4;c++){
      #pragma unroll
      for (int r=0;r<4;r++){
        float m = row16_max_f32(fmaxf(zv[2*c][r], zv[2*c+1][r]));
        if (r15 == 15)
          m3T[(size_t)(base + q*4 + r)*(NB*NS) + blockIdx.x*4 + c] = m;
      }
    }
  }
}

// reduce per-block partials -> BN scale/shift per channel
__global__ __launch_bounds__(256) void mkbn_kernel(const float* __restrict__ partial,
    int nrows, int stride, const float* __restrict__ g, const float* __restrict__ be,
    float* __restrict__ scale, float* __restrict__ shift, float inv_count){
  const int c = blockIdx.x;
  const int C = gridDim.x;
  float s=0.f, q=0.f;
  for (int r=threadIdx.x; r<nrows; r+=256){
    s += partial[(size_t)r*stride + c];
    q += partial[(size_t)r*stride + C + c];
  }
  __shared__ float ls[256], lq[256];
  ls[threadIdx.x]=s; lq[threadIdx.x]=q;
  __syncthreads();
  for (int off=128; off>0; off>>=1){
    if (threadIdx.x < off){ ls[threadIdx.x]+=ls[threadIdx.x+off]; lq[threadIdx.x]+=lq[threadIdx.x+off]; }
    __syncthreads();
  }
  if (threadIdx.x==0){
    float mean = ls[0]*inv_count;
    float var  = lq[0]*inv_count - mean*mean;
    float sc = g[c]*rsqrtf(var + EPSV);
    scale[c]=sc; shift[c]=be[c]-mean*sc;
  }
}

// out[b,ch,s] = relu(scale3*maxz + shift3) * relu(bn_d(wd*dcen+bd))
// vectorized x4 along s; m3T [ch][b*1024+s] -> coalesced b128 both sides.
__global__ __launch_bounds__(256) void final_kernel(const float* __restrict__ m3T,
    const float* __restrict__ dcen, const float* __restrict__ scale3,
    const float* __restrict__ shift3, const float* __restrict__ wd,
    const float* __restrict__ bd, const float* __restrict__ gd,
    const float* __restrict__ bed, const float* __restrict__ dstat,
    float* __restrict__ out){
  int t = blockIdx.x*256 + threadIdx.x;   // 524288 threads x 4 elems
  int s0 = (t & 255) * 4;
  int ch = (t >> 8) & 127;
  int b  = t >> 15;
  float mean_d = dstat[0], var_d = dstat[1];
  float w = wd[ch];
  float meanp = w*mean_d + bd[ch];
  float varp  = w*w*var_d;
  float dsc = gd[ch]*rsqrtf(varp + EPSV);
  float dsh = bed[ch] - meanp*dsc;
  float sc3 = scale3[ch], sh3 = shift3[ch];
  float4 dc = *(const float4*)&dcen[b*NS + s0];
  float4 zv = *(const float4*)&m3T[(size_t)ch*(NB*NS) + b*NS + s0];
  float4 o;
  o.x = fmaxf(sc3*zv.x + sh3, 0.f) * fmaxf(dsc*(w*dc.x + bd[ch]) + dsh, 0.f);
  o.y = fmaxf(sc3*zv.y + sh3, 0.f) * fmaxf(dsc*(w*dc.y + bd[ch]) + dsh, 0.f);
  o.z = fmaxf(sc3*zv.z + sh3, 0.f) * fmaxf(dsc*(w*dc.z + bd[ch]) + dsh, 0.f);
  o.w = fmaxf(sc3*zv.w + sh3, 0.f) * fmaxf(dsc*(w*dc.w + bd[ch]) + dsh, 0.f);
  *(float4*)&out[(size_t)t*4] = o;
}

// ---------------------------------------------------------------------------
extern "C" void kernel_launch(void* const* d_in, const int* in_sizes, int n_in,
                              void* d_out, int out_size, void* d_ws, size_t ws_size,
                              hipStream_t stream){
  const float* xyz     = (const float*)d_in[0];
  const float* points  = (const float*)d_in[1];
  const float* density = (const float*)d_in[2];
  const float* w0 = (const float*)d_in[3];
  const float* b0 = (const float*)d_in[4];
  const float* g0 = (const float*)d_in[5];
  const float* be0= (const float*)d_in[6];
  const float* w1 = (const float*)d_in[7];
  const float* b1 = (const float*)d_in[8];
  const float* g1 = (const float*)d_in[9];
  const float* be1= (const float*)d_in[10];
  const float* w2 = (const float*)d_in[11];
  const float* b2 = (const float*)d_in[12];
  const float* g2 = (const float*)d_in[13];
  const float* be2= (const float*)d_in[14];
  const float* wd = (const float*)d_in[15];
  const float* bd = (const float*)d_in[16];
  const float* gd = (const float*)d_in[17];
  const float* bed= (const float*)d_in[18];

  float* out = (float*)d_out;
  float* newxyz = out;                 // (B,S,3) = output 0
  float* out1   = out + (size_t)NB*NS*3;

  // workspace layout
  unsigned short* ptsT = (unsigned short*)d_ws;          // 4,194,304 u16
  float4* xyz4 = (float4*)(ptsT + (size_t)NB*NN*NCF);    // 65,536 float4
  int*   fidx = (int*)(xyz4 + (size_t)NB*NN);            // 16,384 i
  float* dcen = (float*)(fidx + NB*NS);                  // 16,384 f
  int*   kidx = (int*)(dcen + NB*NS);                    // 524,288 i
  unsigned short* z1 = (unsigned short*)(kidx + NPTS);   // 33,554,432 u16
  unsigned short* z2 = z1 + (size_t)NPTS*64;             // 33,554,432 u16
  float* m3T  = (float*)(z2 + (size_t)NPTS*64);          // 2,097,152 f
  float* p1   = m3T + (size_t)NB*NS*128;                 // 4096*128 f
  float* p2   = p1 + 4096*128;                           // 4096*128 f
  float* p3   = p2 + 4096*128;                           // 4096*256 f
  float* bnp  = p3 + 4096*256;                           // 512 f
  float* dstat= bnp + 512;                               // 2 f
  unsigned short* w0p = (unsigned short*)(dstat + 2);    // 8192 u16
  unsigned short* w1p = w0p + 64*128;                    // 4096 u16
  unsigned short* w2p = w1p + 64*64;                     // 8192 u16

  hipLaunchKernelGGL(prep_kernel,  dim3(256),  dim3(256), 0, stream, points, xyz, ptsT, xyz4,
                     w0, w1, w2, w0p, w1p, w2p);
  hipLaunchKernelGGL(fps_kernel,   dim3(NB),   dim3(FT),  0, stream, xyz4, fidx, newxyz);
  hipLaunchKernelGGL(dcen_kernel,  dim3(64),   dim3(256), 0, stream, density, fidx, dcen);
  hipLaunchKernelGGL(dstats_kernel,dim3(1),    dim3(256), 0, stream, dcen, dstat);
  hipLaunchKernelGGL(knn_kernel,   dim3(4096), dim3(256), 0, stream, xyz4, newxyz, kidx);
  hipLaunchKernelGGL(conv1_kernel, dim3(4096), dim3(256), 0, stream, xyz4, ptsT, newxyz, kidx, w0p, b0, z1, p1);
  hipLaunchKernelGGL(mkbn_kernel,  dim3(64),   dim3(256), 0, stream, p1, 4096, 128, g0, be0, bnp+0,   bnp+64,  1.0f/(float)NPTS);
  hipLaunchKernelGGL(conv2_kernel, dim3(4096), dim3(256), 0, stream, z1, w1p, b1, bnp+0, bnp+64, z2, p2);
  hipLaunchKernelGGL(mkbn_kernel,  dim3(64),   dim3(256), 0, stream, p2, 4096, 128, g1, be1, bnp+128, bnp+192, 1.0f/(float)NPTS);
  hipLaunchKernelGGL(conv3_kernel, dim3(4096), dim3(256), 0, stream, z2, w2p, b2, bnp+128, bnp+192, m3T, p3);
  hipLaunchKernelGGL(mkbn_kernel,  dim3(128),  dim3(256), 0, stream, p3, 4096, 256, g2, be2, bnp+256, bnp+384, 1.0f/(float)NPTS);
  hipLaunchKernelGGL(final_kernel, dim3(2048), dim3(256), 0, stream, m3T, dcen, bnp+256, bnp+384, wd, bd, gd, bed, dstat, out1);
}